// Round 5
// baseline (193.472 us; speedup 1.0000x reference)
//
#include <hip/hip_runtime.h>

#define N2 4096
#define D 128
#define TAU_INV 10.0f
#define K2 14.4269504088896340736f   // TAU_INV * log2(e)
#define JSL 16
#define MAIN_BLOCKS (128 * JSL)

typedef __attribute__((ext_vector_type(8))) short bf16x8;
typedef __attribute__((ext_vector_type(16))) float floatx16;

__device__ __forceinline__ short f2bf(float f) {
    unsigned u = __float_as_uint(f);
    u = (u + 0x7fff + ((u >> 16) & 1)) >> 16;   // RNE
    return (short)u;
}

// Normalize p = concat(z_i,z_j) -> bf16 qb, labels; zero stats (se|sp) + ticket.
__global__ __launch_bounds__(256) void prep_kernel(const float* __restrict__ zi,
                                                   const float* __restrict__ zj,
                                                   const long long* __restrict__ y,
                                                   short* __restrict__ qb,
                                                   int* __restrict__ labels,
                                                   float* __restrict__ stats,
                                                   int* __restrict__ ticket) {
    int b = blockIdx.x;                 // 512 blocks, 8 rows each
    int tid = threadIdx.x;
    int wave = tid >> 6, lane = tid & 63;
    int l32 = lane & 31;
    int row = b * 8 + wave * 2 + (lane >> 5);
    const float* src = (row < 2048) ? (zi + row * D) : (zj + (row - 2048) * D);
    float4 v = ((const float4*)src)[l32];
    float ss = v.x * v.x + v.y * v.y + v.z * v.z + v.w * v.w;
    #pragma unroll
    for (int m = 1; m < 32; m <<= 1) ss += __shfl_xor(ss, m);
    float inv = rsqrtf(ss);             // ||p|| ~ sqrt(128) >> eps
    short4 o;
    o.x = f2bf(v.x * inv); o.y = f2bf(v.y * inv);
    o.z = f2bf(v.z * inv); o.w = f2bf(v.w * inv);
    ((short4*)(qb + row * D))[l32] = o;
    if (tid < 8) { int r2 = b * 8 + tid; labels[r2] = (int)y[r2 & 2047]; }
    if (tid < 16) stats[b * 16 + tid] = 0.f;     // 8192 floats = se | sp
    if (b == 0 && tid == 0) *ticket = 0;
}

// Fused sim-GEMM + masked-softmax row stats + last-block finish.
// Block: i-tile (32 rows) x 256-col j-slice. Wave w: j-tiles w, w+4 (32 cols each).
// MFMA 32x32x16 bf16; C/D: col=lane&31, row=(r&3)+8*(r>>2)+4*(lane>>5).
// stats[0..4095] = se (sum exp, self excl), stats[4096..8191] = sp (sum pos raw dots).
__global__ __launch_bounds__(256) void main_kernel(const short* __restrict__ qb,
                                                   const int* __restrict__ labels,
                                                   float* __restrict__ stats,
                                                   int* __restrict__ ticket,
                                                   float* __restrict__ out) {
    int tid = threadIdx.x;
    int wave = tid >> 6, lane = tid & 63;
    int col = lane & 31, half = lane >> 5;
    int it = blockIdx.x >> 4, js = blockIdx.x & (JSL - 1);
    int i0 = it * 32;

    const short* ap = qb + (i0 + col) * D + half * 8;
    bf16x8 af[8];
    #pragma unroll
    for (int k = 0; k < 8; ++k) af[k] = *(const bf16x8*)(ap + k * 16);

    int rl[16];
    #pragma unroll
    for (int r = 0; r < 16; ++r) rl[r] = labels[i0 + (r & 3) + 8 * (r >> 2) + 4 * half];

    float se[16], sp[16];
    #pragma unroll
    for (int r = 0; r < 16; ++r) { se[r] = 0.f; sp[r] = 0.f; }

    for (int t = 0; t < 2; ++t) {
        int j0 = js * (N2 / JSL) + (wave + 4 * t) * 32;
        const short* bp = qb + (j0 + col) * D + half * 8;
        bf16x8 bf[8];
        #pragma unroll
        for (int k = 0; k < 8; ++k) bf[k] = *(const bf16x8*)(bp + k * 16);

        floatx16 acc;
        #pragma unroll
        for (int r = 0; r < 16; ++r) acc[r] = 0.f;
        #pragma unroll
        for (int k = 0; k < 8; ++k)
            acc = __builtin_amdgcn_mfma_f32_32x32x16_bf16(af[k], bf[k], acc, 0, 0, 0);

        int jcol = j0 + col;
        int cl = labels[jcol];
        #pragma unroll
        for (int r = 0; r < 16; ++r) {
            int rowr = i0 + (r & 3) + 8 * (r >> 2) + 4 * half;
            bool self = (rowr == jcol);
            float e = __builtin_amdgcn_exp2f(acc[r] * K2);
            se[r] += self ? 0.f : e;
            bool pos = (rl[r] == cl) && !self;
            sp[r] += pos ? acc[r] : 0.f;   // raw dot; TAU_INV applied in finish
        }
    }

    // Transposed butterfly reduce over the 32 cols (per 32-lane half):
    // 32 regs (se|sp) -> 1 reg; lane l (l=col) ends holding the full col-sum of
    // v[l]: l<16 -> se[l], l>=16 -> sp[l-16]. Then ONE wave atomic.
    float v[32];
    #pragma unroll
    for (int i = 0; i < 16; ++i) { v[i] = se[i]; v[16 + i] = sp[i]; }
    #pragma unroll
    for (int k = 0; k < 5; ++k) {
        int m = 1 << k;
        #pragma unroll
        for (int i = 0; i < 32; ++i) {
            if ((i & m) == 0) {
                float keep = (lane & m) ? v[i | m] : v[i];
                float send = (lane & m) ? v[i]     : v[i | m];
                v[i] = keep + __shfl_xor(send, m);
            }
        }
    }
    {
        int q = col >> 4;                 // 0: se, 1: sp
        int r = col & 15;
        int rowg = i0 + (r & 3) + 8 * (r >> 2) + 4 * half;
        atomicAdd(&stats[q * N2 + rowg], v[0]);
    }

    // ---- last-block finish (ticket) ----
    __shared__ int is_last;
    __syncthreads();
    if (tid == 0) {
        __threadfence();                          // release our atomics
        int old = atomicAdd(ticket, 1);
        is_last = (old == MAIN_BLOCKS - 1);
    }
    __syncthreads();
    if (!is_last) return;
    __threadfence();                              // acquire others' atomics

    __shared__ int hist[10];
    if (tid < 10) hist[tid] = 0;
    __syncthreads();
    for (int i = tid; i < 2048; i += 256) atomicAdd(&hist[labels[i]], 1);
    __syncthreads();

    float local = 0.f;
    for (int r = tid; r < N2; r += 256) {
        float cnt = (float)(2 * hist[labels[r]] - 1);
        local += (stats[N2 + r] * TAU_INV) / cnt - __logf(stats[r]);
    }
    #pragma unroll
    for (int m = 1; m < 64; m <<= 1) local += __shfl_xor(local, m);
    __shared__ float wsum[4];
    if (lane == 0) wsum[wave] = local;
    __syncthreads();
    if (tid == 0) out[0] = -(wsum[0] + wsum[1] + wsum[2] + wsum[3]) * (1.0f / (float)N2);
}

extern "C" void kernel_launch(void* const* d_in, const int* in_sizes, int n_in,
                              void* d_out, int out_size, void* d_ws, size_t ws_size,
                              hipStream_t stream) {
    const float*     zi = (const float*)d_in[0];
    const float*     zj = (const float*)d_in[1];
    const long long* y  = (const long long*)d_in[2];
    float* out = (float*)d_out;

    char* ws = (char*)d_ws;
    short* qb     = (short*)ws;                               // 1 MB
    int*   labels = (int*)(ws + N2 * D * sizeof(short));      // 16 KB
    float* stats  = (float*)(ws + N2 * D * sizeof(short) + N2 * sizeof(int)); // 32 KB
    int*   ticket = (int*)(stats + 2 * N2);

    prep_kernel<<<512, 256, 0, stream>>>(zi, zj, y, qb, labels, stats, ticket);
    main_kernel<<<MAIN_BLOCKS, 256, 0, stream>>>(qb, labels, stats, ticket, out);
}

// Round 6
// 110.125 us; speedup vs baseline: 1.7568x; 1.7568x over previous
//
#include <hip/hip_runtime.h>

#define N2 4096
#define D 128
#define TAU_INV 10.0f
#define K2 14.4269504088896340736f   // TAU_INV * log2(e)
#define JSL 8
#define MAIN_BLOCKS (128 * JSL)

typedef __attribute__((ext_vector_type(8))) short bf16x8;
typedef __attribute__((ext_vector_type(16))) float floatx16;

__device__ __forceinline__ short f2bf(float f) {
    unsigned u = __float_as_uint(f);
    u = (u + 0x7fff + ((u >> 16) & 1)) >> 16;   // RNE
    return (short)u;
}

// Normalize p = concat(z_i,z_j) -> bf16 qb, labels; zero stats (se|sp) + ticket.
__global__ __launch_bounds__(256) void prep_kernel(const float* __restrict__ zi,
                                                   const float* __restrict__ zj,
                                                   const long long* __restrict__ y,
                                                   short* __restrict__ qb,
                                                   int* __restrict__ labels,
                                                   float* __restrict__ stats,
                                                   int* __restrict__ ticket) {
    int b = blockIdx.x;                 // 512 blocks, 8 rows each
    int tid = threadIdx.x;
    int wave = tid >> 6, lane = tid & 63;
    int l32 = lane & 31;
    int row = b * 8 + wave * 2 + (lane >> 5);
    const float* src = (row < 2048) ? (zi + row * D) : (zj + (row - 2048) * D);
    float4 v = ((const float4*)src)[l32];
    float ss = v.x * v.x + v.y * v.y + v.z * v.z + v.w * v.w;
    #pragma unroll
    for (int m = 1; m < 32; m <<= 1) ss += __shfl_xor(ss, m);
    float inv = rsqrtf(ss);             // ||p|| ~ sqrt(128) >> eps
    short4 o;
    o.x = f2bf(v.x * inv); o.y = f2bf(v.y * inv);
    o.z = f2bf(v.z * inv); o.w = f2bf(v.w * inv);
    ((short4*)(qb + row * D))[l32] = o;
    if (tid < 8) { int r2 = b * 8 + tid; labels[r2] = (int)y[r2 & 2047]; }
    if (tid < 16) stats[b * 16 + tid] = 0.f;     // 8192 floats = se | sp
    if (b == 0 && tid == 0) *ticket = 0;
}

// Fused sim-GEMM + masked-softmax row stats + last-block finish.
// Block: i-tile (32 rows) x 512-col j-slice. Wave w: j-tiles w,w+4,w+8,w+12.
// MFMA 32x32x16 bf16; C/D: col=lane&31, row=(r&3)+8*(r>>2)+4*(lane>>5).
// stats[0..4095] = se (sum exp, self excl), stats[4096..8191] = sp (sum pos raw dots).
__global__ __launch_bounds__(256) void main_kernel(const short* __restrict__ qb,
                                                   const int* __restrict__ labels,
                                                   float* __restrict__ stats,
                                                   int* __restrict__ ticket,
                                                   float* __restrict__ out) {
    int tid = threadIdx.x;
    int wave = tid >> 6, lane = tid & 63;
    int col = lane & 31, half = lane >> 5;
    int it = blockIdx.x >> 3, js = blockIdx.x & (JSL - 1);
    int i0 = it * 32;
    int jbase = js * (N2 / JSL);

    const short* ap = qb + (i0 + col) * D + half * 8;
    bf16x8 af[8];
    #pragma unroll
    for (int k = 0; k < 8; ++k) af[k] = *(const bf16x8*)(ap + k * 16);

    int rl[16];
    #pragma unroll
    for (int r = 0; r < 16; ++r) rl[r] = labels[i0 + (r & 3) + 8 * (r >> 2) + 4 * half];

    float se[16], sp[16];
    #pragma unroll
    for (int r = 0; r < 16; ++r) { se[r] = 0.f; sp[r] = 0.f; }

    // software-pipelined over 4 j-tiles: prefetch t+1's B-frags before t's MFMA chain
    bf16x8 bufA[8], bufB[8];
    {
        const short* bp = qb + (jbase + wave * 32 + col) * D + half * 8;
        #pragma unroll
        for (int k = 0; k < 8; ++k) bufA[k] = *(const bf16x8*)(bp + k * 16);
    }

    #pragma unroll
    for (int t = 0; t < 4; ++t) {
        if (t < 3) {
            const short* bpn = qb + (jbase + (wave + 4 * (t + 1)) * 32 + col) * D + half * 8;
            #pragma unroll
            for (int k = 0; k < 8; ++k) bufB[k] = *(const bf16x8*)(bpn + k * 16);
        }

        floatx16 acc;
        #pragma unroll
        for (int r = 0; r < 16; ++r) acc[r] = 0.f;
        #pragma unroll
        for (int k = 0; k < 8; ++k)
            acc = __builtin_amdgcn_mfma_f32_32x32x16_bf16(af[k], bufA[k], acc, 0, 0, 0);

        int jcol = jbase + (wave + 4 * t) * 32 + col;
        int cl = labels[jcol];
        #pragma unroll
        for (int r = 0; r < 16; ++r) {
            int rowr = i0 + (r & 3) + 8 * (r >> 2) + 4 * half;
            bool self = (rowr == jcol);
            float e = __builtin_amdgcn_exp2f(acc[r] * K2);
            se[r] += self ? 0.f : e;
            bool pos = (rl[r] == cl) && !self;
            sp[r] += pos ? acc[r] : 0.f;   // raw dot; TAU_INV applied in finish
        }

        #pragma unroll
        for (int k = 0; k < 8; ++k) bufA[k] = bufB[k];
    }

    // simple per-row shuffle reduce across the 32 cols (proven in R2)
    #pragma unroll
    for (int r = 0; r < 16; ++r) {
        float a = se[r], b = sp[r];
        #pragma unroll
        for (int m = 1; m < 32; m <<= 1) {
            a += __shfl_xor(a, m);
            b += __shfl_xor(b, m);
        }
        if (col == 0) {
            int rowr = i0 + (r & 3) + 8 * (r >> 2) + 4 * half;
            atomicAdd(&stats[rowr], a);
            atomicAdd(&stats[N2 + rowr], b);
        }
    }

    // ---- last-block finish (ticket) ----
    __shared__ int is_last;
    __syncthreads();
    if (tid == 0) {
        __threadfence();                          // release our atomics
        int old = atomicAdd(ticket, 1);
        is_last = (old == MAIN_BLOCKS - 1);
    }
    __syncthreads();
    if (!is_last) return;
    __threadfence();                              // acquire others' atomics

    __shared__ int hist[10];
    if (tid < 10) hist[tid] = 0;
    __syncthreads();
    for (int i = tid; i < 2048; i += 256) atomicAdd(&hist[labels[i]], 1);
    __syncthreads();

    float local = 0.f;
    for (int r = tid; r < N2; r += 256) {
        float cnt = (float)(2 * hist[labels[r]] - 1);
        local += (stats[N2 + r] * TAU_INV) / cnt - __logf(stats[r]);
    }
    #pragma unroll
    for (int m = 1; m < 64; m <<= 1) local += __shfl_xor(local, m);
    __shared__ float wsum[4];
    if (lane == 0) wsum[wave] = local;
    __syncthreads();
    if (tid == 0) out[0] = -(wsum[0] + wsum[1] + wsum[2] + wsum[3]) * (1.0f / (float)N2);
}

extern "C" void kernel_launch(void* const* d_in, const int* in_sizes, int n_in,
                              void* d_out, int out_size, void* d_ws, size_t ws_size,
                              hipStream_t stream) {
    const float*     zi = (const float*)d_in[0];
    const float*     zj = (const float*)d_in[1];
    const long long* y  = (const long long*)d_in[2];
    float* out = (float*)d_out;

    char* ws = (char*)d_ws;
    short* qb     = (short*)ws;                               // 1 MB
    int*   labels = (int*)(ws + N2 * D * sizeof(short));      // 16 KB
    float* stats  = (float*)(ws + N2 * D * sizeof(short) + N2 * sizeof(int)); // 32 KB
    int*   ticket = (int*)(stats + 2 * N2);

    prep_kernel<<<512, 256, 0, stream>>>(zi, zj, y, qb, labels, stats, ticket);
    main_kernel<<<MAIN_BLOCKS, 256, 0, stream>>>(qb, labels, stats, ticket, out);
}